// Round 4
// baseline (208.739 us; speedup 1.0000x reference)
//
#include <hip/hip_runtime.h>

// Problem: y = relu(x @ (w1*m)^T + b1) @ (w2*m^T)^T + b2
// x:[131072,256] f32, w1:[1024,256], b1:[1024], w2:[256,1024], b2:[256], mask:[1024,256] i32
// bf16 MFMA 32x32x16, hidden chunks of 32, MT=128 (4 waves).
// Round-4 structure: LDS-read pipe is the top resource (~62%) and occupancy is
// register-pinned at 2 waves/SIMD (128 VGPR + 128 acc-AGPR, unified file). So:
//  - fc2 wave-specialized over output cols (wave w -> cols [64w,64w+64), ALL 128 rows):
//    fc2-B reads per block-chunk drop 64 -> 16 (B-frags hoisted, reused over row groups);
//    per-wave LDS reads 34 -> 28.
//  - Hc is block-shared (mid-chunk barrier replaces threadfence; still 2 barriers/chunk).
//  - fc1 split into 2 independent MFMA chains (dep-latency > issue at 2 waves/SIMD).
//  - s_setprio around MFMA clusters.
// Lessons kept: weights via LDS (round 2: direct-global B is latency-toxic); dbuf staging
// (neutral but harmless, keeps single drain point per barrier).

#define D_MODEL 256
#define D_HID   1024
#define MT      128     // rows per block (4 waves; fc1: 32 rows/wave, fc2: 64 cols/wave)
#define NCHUNK  32      // hidden chunks of 32
#define CHUNK_ELEMS 8192 // 32*256 bf16 elems per chunk per weight (16 KB)

typedef __attribute__((ext_vector_type(8))) short short8;
typedef __attribute__((ext_vector_type(16))) float f32x16;

__device__ __forceinline__ unsigned short f2bf(float f) {
  union { float f; unsigned int u; } v; v.f = f;
  unsigned int u = v.u;
  return (unsigned short)((u + 0x7FFFu + ((u >> 16) & 1u)) >> 16);  // RNE
}

__device__ __forceinline__ void async16(void* lds, const void* g) {
  __builtin_amdgcn_global_load_lds(
      (const __attribute__((address_space(1))) unsigned int*)g,
      (__attribute__((address_space(3))) unsigned int*)lds,
      16, 0, 0);
}

// ---------------- prep: mask+cast+swizzle weights into 32x32x16 B-frag order --------
// W1p slot t = (c*16+kf)*64+lane holds W1eff[h=c*32+(lane&31)][k=kf*16+(lane>>5)*8+j], j=0..7
// W2p slot s = ((c*8+cf)*2+kf2)*64+lane holds W2eff[n=cf*32+(lane&31)][h=c*32+kf2*16+(lane>>5)*8+j]
__global__ __launch_bounds__(256) void prep_weights(
    const float* __restrict__ w1, const float* __restrict__ w2,
    const int* __restrict__ mask,
    unsigned short* __restrict__ W1p, unsigned short* __restrict__ W2p)
{
  int t = blockIdx.x * 256 + threadIdx.x;   // 0..65535
  if (t < 32768) {
    int c    = t >> 10;
    int kf   = (t >> 6) & 15;
    int lane = t & 63;
    int h = c * 32 + (lane & 31);
    int k = kf * 16 + (lane >> 5) * 8;
    const float* wp = w1 + h * 256 + k;
    const int*   mp = mask + h * 256 + k;
    short8 v;
    #pragma unroll
    for (int j = 0; j < 8; ++j) v[j] = (short)(mp[j] ? f2bf(wp[j]) : 0);
    *(short8*)(W1p + (size_t)t * 8) = v;
  } else {
    int s    = t - 32768;
    int c    = s >> 10;
    int cf   = (s >> 7) & 7;
    int kf2  = (s >> 6) & 1;
    int lane = s & 63;
    int n = cf * 32 + (lane & 31);
    int h = c * 32 + kf2 * 16 + (lane >> 5) * 8;
    short8 v;
    #pragma unroll
    for (int j = 0; j < 8; ++j)
      v[j] = (short)(mask[(h + j) * 256 + n] ? f2bf(w2[n * 1024 + h + j]) : 0);
    *(short8*)(W2p + (size_t)s * 8) = v;
  }
}

// ---------------- fused main kernel ----------------
__global__ __launch_bounds__(256, 2) void ffd_fused(
    const float* __restrict__ X, const float* __restrict__ b1,
    const float* __restrict__ b2,
    const unsigned short* __restrict__ W1p, const unsigned short* __restrict__ W2p,
    float* __restrict__ Y)
{
  __shared__ unsigned short sW1[2][CHUNK_ELEMS];  // 32 KB, dbuf, B-frag order
  __shared__ unsigned short sW2[2][CHUNK_ELEMS];  // 32 KB, dbuf, B-frag order
  __shared__ unsigned short sHc[MT * 32];         // 8 KB, block-shared [128][32], XOR-swz

  const int tid  = threadIdx.x;
  const int lane = tid & 63;
  const int w    = tid >> 6;
  const int l32  = lane & 31;
  const int q2   = lane >> 5;

  const long blockRow = (long)blockIdx.x * MT;
  const long rowBase  = blockRow + w * 32;   // fc1 rows owned by this wave

  // X A-fragments (full K=256) in registers: xf[kf][j] = X[row][kf*16 + q2*8 + j]
  short8 xf[16];
  const float* xrow = X + (rowBase + l32) * D_MODEL;
  #pragma unroll
  for (int kf = 0; kf < 16; ++kf) {
    const float4 f0 = *(const float4*)(xrow + kf * 16 + q2 * 8);
    const float4 f1 = *(const float4*)(xrow + kf * 16 + q2 * 8 + 4);
    short8 v;
    v[0] = (short)f2bf(f0.x); v[1] = (short)f2bf(f0.y);
    v[2] = (short)f2bf(f0.z); v[3] = (short)f2bf(f0.w);
    v[4] = (short)f2bf(f1.x); v[5] = (short)f2bf(f1.y);
    v[6] = (short)f2bf(f1.z); v[7] = (short)f2bf(f1.w);
    xf[kf] = v;
  }

  // acc[cf_local][row_group]: wave w owns output cols [w*64, w*64+64), all 128 rows
  f32x16 acc[2][4];
  #pragma unroll
  for (int i = 0; i < 2; ++i)
    #pragma unroll
    for (int g = 0; g < 4; ++g)
      #pragma unroll
      for (int j = 0; j < 16; ++j) acc[i][g][j] = 0.f;

  // prologue: stage chunk 0 into buffer 0
  {
    const unsigned short* g1 = W1p + tid * 8;
    const unsigned short* g2 = W2p + tid * 8;
    #pragma unroll
    for (int i = 0; i < 4; ++i) {
      async16(&sW1[0][i * 2048 + tid * 8], g1 + i * 2048);
      async16(&sW2[0][i * 2048 + tid * 8], g2 + i * 2048);
    }
  }
  __syncthreads();   // chunk 0 staged

  for (int c = 0; c < NCHUNK; ++c) {
    const int cur = c & 1;

    // issue stage(c+1) into the other buffer (drained at the mid-chunk barrier,
    // after ~fc1's worth of work; W1p/W2p are L2-hot)
    if (c + 1 < NCHUNK) {
      const unsigned short* g1 = W1p + (size_t)(c + 1) * CHUNK_ELEMS + tid * 8;
      const unsigned short* g2 = W2p + (size_t)(c + 1) * CHUNK_ELEMS + tid * 8;
      unsigned short* d1 = &sW1[cur ^ 1][tid * 8];
      unsigned short* d2 = &sW2[cur ^ 1][tid * 8];
      #pragma unroll
      for (int i = 0; i < 4; ++i) {
        async16(d1 + i * 2048, g1 + i * 2048);
        async16(d2 + i * 2048, g2 + i * 2048);
      }
    }
    const float bb = b1[c * 32 + l32];

    // fc1: Hc[32 rows (this wave)][32 hidden]; 2 independent MFMA chains
    f32x16 h0, h1;
    #pragma unroll
    for (int j = 0; j < 16; ++j) { h0[j] = 0.f; h1[j] = 0.f; }
    __builtin_amdgcn_s_setprio(1);
    #pragma unroll
    for (int kf = 0; kf < 8; ++kf) {
      short8 bfa = *(const short8*)&sW1[cur][kf * 512 + lane * 8];
      short8 bfb = *(const short8*)&sW1[cur][(kf + 8) * 512 + lane * 8];
      h0 = __builtin_amdgcn_mfma_f32_32x32x16_bf16(xf[kf],     bfa, h0, 0, 0, 0);
      h1 = __builtin_amdgcn_mfma_f32_32x32x16_bf16(xf[kf + 8], bfb, h1, 0, 0, 0);
    }
    __builtin_amdgcn_s_setprio(0);

    // bias + relu, C-layout -> XOR-swizzled block-shared bf16 scratch
    #pragma unroll
    for (int r = 0; r < 16; ++r) {
      int R = w * 32 + (r & 3) + 8 * (r >> 2) + 4 * q2;   // global row in block
      float v = h0[r] + h1[r] + bb;
      v = v > 0.f ? v : 0.f;
      sHc[(R * 32 + l32) ^ ((R & 14) << 2)] = f2bf(v);
    }
    __syncthreads();   // Hc ready for all waves; stage(c+1) drained here

    // fc2: acc[2][4] += Hc(all rows) @ W2c^T(cols w*64..w*64+63)
    // B-frags hoisted (4 reads), reused across the 4 row groups.
    short8 bf2[2][2];
    #pragma unroll
    for (int kf2 = 0; kf2 < 2; ++kf2)
      #pragma unroll
      for (int cfl = 0; cfl < 2; ++cfl)
        bf2[kf2][cfl] = *(const short8*)&sW2[cur][((w * 2 + cfl) * 2 + kf2) * 512 + lane * 8];

    __builtin_amdgcn_s_setprio(1);
    #pragma unroll
    for (int rg = 0; rg < 4; ++rg) {
      #pragma unroll
      for (int kf2 = 0; kf2 < 2; ++kf2) {
        int R = rg * 32 + l32;
        short8 af = *(const short8*)&sHc[(R * 32 + kf2 * 16 + q2 * 8) ^ ((R & 14) << 2)];
        acc[0][rg] = __builtin_amdgcn_mfma_f32_32x32x16_bf16(af, bf2[kf2][0], acc[0][rg], 0, 0, 0);
        acc[1][rg] = __builtin_amdgcn_mfma_f32_32x32x16_bf16(af, bf2[kf2][1], acc[1][rg], 0, 0, 0);
      }
    }
    __builtin_amdgcn_s_setprio(0);

    __syncthreads();  // sHc + buf[cur] fully consumed before next chunk overwrites
  }

  // epilogue: + b2, store fp32 (wave w -> cols [w*64, w*64+64), all 128 rows)
  #pragma unroll
  for (int cfl = 0; cfl < 2; ++cfl) {
    int col = w * 64 + cfl * 32 + l32;
    float bias = b2[col];
    #pragma unroll
    for (int rg = 0; rg < 4; ++rg) {
      #pragma unroll
      for (int r = 0; r < 16; ++r) {
        long row = blockRow + rg * 32 + (r & 3) + 8 * (r >> 2) + 4 * q2;
        Y[row * D_MODEL + col] = acc[cfl][rg][r] + bias;
      }
    }
  }
}

extern "C" void kernel_launch(void* const* d_in, const int* in_sizes, int n_in,
                              void* d_out, int out_size, void* d_ws, size_t ws_size,
                              hipStream_t stream) {
  const float* x    = (const float*)d_in[0];
  const float* w1   = (const float*)d_in[1];
  const float* b1   = (const float*)d_in[2];
  const float* w2   = (const float*)d_in[3];
  const float* b2   = (const float*)d_in[4];
  const int*   mask = (const int*)d_in[5];

  unsigned short* W1p = (unsigned short*)d_ws;          // 512 KB
  unsigned short* W2p = W1p + (size_t)D_HID * D_MODEL;  // 512 KB
  float* Y = (float*)d_out;

  prep_weights<<<256, 256, 0, stream>>>(w1, w2, mask, W1p, W2p);
  ffd_fused<<<131072 / MT, 256, 0, stream>>>(x, b1, b2, W1p, W2p, Y);
}

// Round 5
// 163.820 us; speedup vs baseline: 1.2742x; 1.2742x over previous
//
#include <hip/hip_runtime.h>

// Problem: y = relu(x @ (w1*m)^T + b1) @ (w2*m^T)^T + b2
// x:[131072,256] f32, w1:[1024,256], b1:[1024], w2:[256,1024], b2:[256], mask:[1024,256] i32
// bf16 MFMA 32x32x16, hidden chunks of 32, MT=128 (4 waves, wave-private 32 rows).
// Round-5 structure: kernel is latency-bound (no pipe >55%); the chunk critical path ran
// through the Hc LDS transpose. Now fc1 computes Hc^T via SWAPPED operands
// (A/B frag layouts are identical for 32x32x16), bias+relu in C-space, and the fc2
// A-fragment is built IN-REGISTER with v_cvt_pk_bf16_f32 + v_permlane32_swap_b32
// (T12 adaptation) -- no Hc LDS round-trip, no threadfence, no f2bf chain.
// Ledger: direct-global fc2-B = latency-toxic (R2); block-shared Hc + col-specialized
// fc2 = conflict regression (R4); dbuf staging neutral-kept (R3).

#define D_MODEL 256
#define D_HID   1024
#define MT      128     // rows per block (4 waves x 32 rows)
#define NCHUNK  32      // hidden chunks of 32
#define CHUNK_ELEMS 8192 // 32*256 bf16 elems per chunk per weight (16 KB)

typedef __attribute__((ext_vector_type(8))) short short8;
typedef __attribute__((ext_vector_type(16))) float f32x16;
typedef __attribute__((ext_vector_type(4))) unsigned int uint4v;

__device__ __forceinline__ unsigned short f2bf(float f) {
  union { float f; unsigned int u; } v; v.f = f;
  unsigned int u = v.u;
  return (unsigned short)((u + 0x7FFFu + ((u >> 16) & 1u)) >> 16);  // RNE
}

__device__ __forceinline__ unsigned cvtpk_bf16(float lo, float hi) {
  unsigned r;
  asm("v_cvt_pk_bf16_f32 %0, %1, %2" : "=v"(r) : "v"(lo), "v"(hi));
  return r;
}

__device__ __forceinline__ void plswap(unsigned &a, unsigned &b) {
  asm("v_permlane32_swap_b32 %0, %1" : "+v"(a), "+v"(b));
}

__device__ __forceinline__ void async16(void* lds, const void* g) {
  __builtin_amdgcn_global_load_lds(
      (const __attribute__((address_space(1))) unsigned int*)g,
      (__attribute__((address_space(3))) unsigned int*)lds,
      16, 0, 0);
}

// ---------------- prep: mask+cast+swizzle weights into 32x32x16 B-frag order --------
// W1p slot t = (c*16+kf)*64+lane holds W1eff[h=c*32+(lane&31)][k=kf*16+(lane>>5)*8+j], j=0..7
// W2p slot s = ((c*8+cf)*2+kf2)*64+lane holds W2eff[n=cf*32+(lane&31)][h=c*32+kf2*16+(lane>>5)*8+j]
__global__ __launch_bounds__(256) void prep_weights(
    const float* __restrict__ w1, const float* __restrict__ w2,
    const int* __restrict__ mask,
    unsigned short* __restrict__ W1p, unsigned short* __restrict__ W2p)
{
  int t = blockIdx.x * 256 + threadIdx.x;   // 0..65535
  if (t < 32768) {
    int c    = t >> 10;
    int kf   = (t >> 6) & 15;
    int lane = t & 63;
    int h = c * 32 + (lane & 31);
    int k = kf * 16 + (lane >> 5) * 8;
    const float* wp = w1 + h * 256 + k;
    const int*   mp = mask + h * 256 + k;
    short8 v;
    #pragma unroll
    for (int j = 0; j < 8; ++j) v[j] = (short)(mp[j] ? f2bf(wp[j]) : 0);
    *(short8*)(W1p + (size_t)t * 8) = v;
  } else {
    int s    = t - 32768;
    int c    = s >> 10;
    int cf   = (s >> 7) & 7;
    int kf2  = (s >> 6) & 1;
    int lane = s & 63;
    int n = cf * 32 + (lane & 31);
    int h = c * 32 + kf2 * 16 + (lane >> 5) * 8;
    short8 v;
    #pragma unroll
    for (int j = 0; j < 8; ++j)
      v[j] = (short)(mask[(h + j) * 256 + n] ? f2bf(w2[n * 1024 + h + j]) : 0);
    *(short8*)(W2p + (size_t)s * 8) = v;
  }
}

// ---------------- fused main kernel ----------------
__global__ __launch_bounds__(256, 2) void ffd_fused(
    const float* __restrict__ X, const float* __restrict__ b1,
    const float* __restrict__ b2,
    const unsigned short* __restrict__ W1p, const unsigned short* __restrict__ W2p,
    float* __restrict__ Y)
{
  __shared__ unsigned short sW1[2][CHUNK_ELEMS];  // 32 KB, dbuf, frag order
  __shared__ unsigned short sW2[2][CHUNK_ELEMS];  // 32 KB, dbuf, frag order
  __shared__ float sB1[D_HID];                    // 4 KB, b1 staged once

  const int tid  = threadIdx.x;
  const int lane = tid & 63;
  const int w    = tid >> 6;
  const int l32  = lane & 31;
  const int q2   = lane >> 5;

  const long rowBase = (long)blockIdx.x * MT + w * 32;

  // X fragments (full K=256) in registers: xf[kf][j] = X[rowBase+l32][kf*16 + q2*8 + j]
  short8 xf[16];
  const float* xrow = X + (rowBase + l32) * D_MODEL;
  #pragma unroll
  for (int kf = 0; kf < 16; ++kf) {
    const float4 f0 = *(const float4*)(xrow + kf * 16 + q2 * 8);
    const float4 f1 = *(const float4*)(xrow + kf * 16 + q2 * 8 + 4);
    short8 v;
    v[0] = (short)f2bf(f0.x); v[1] = (short)f2bf(f0.y);
    v[2] = (short)f2bf(f0.z); v[3] = (short)f2bf(f0.w);
    v[4] = (short)f2bf(f1.x); v[5] = (short)f2bf(f1.y);
    v[6] = (short)f2bf(f1.z); v[7] = (short)f2bf(f1.w);
    xf[kf] = v;
  }

  f32x16 acc[8];
  #pragma unroll
  for (int i = 0; i < 8; ++i)
    #pragma unroll
    for (int j = 0; j < 16; ++j) acc[i][j] = 0.f;

  // prologue: stage b1 (once) + chunk 0 into buffer 0
  async16(&sB1[tid * 4], b1 + tid * 4);
  {
    const unsigned short* g1 = W1p + tid * 8;
    const unsigned short* g2 = W2p + tid * 8;
    #pragma unroll
    for (int i = 0; i < 4; ++i) {
      async16(&sW1[0][i * 2048 + tid * 8], g1 + i * 2048);
      async16(&sW2[0][i * 2048 + tid * 8], g2 + i * 2048);
    }
  }
  __syncthreads();   // chunk 0 + b1 staged

  for (int c = 0; c < NCHUNK; ++c) {
    const int cur = c & 1;

    // issue stage(c+1) into the other buffer; drains at end-of-chunk barrier,
    // hidden under fc1 + pack + fc2 (~1.5k cycles); W1p/W2p are L2-hot
    if (c + 1 < NCHUNK) {
      const unsigned short* g1 = W1p + (size_t)(c + 1) * CHUNK_ELEMS + tid * 8;
      const unsigned short* g2 = W2p + (size_t)(c + 1) * CHUNK_ELEMS + tid * 8;
      unsigned short* d1 = &sW1[cur ^ 1][tid * 8];
      unsigned short* d2 = &sW2[cur ^ 1][tid * 8];
      #pragma unroll
      for (int i = 0; i < 4; ++i) {
        async16(d1 + i * 2048, g1 + i * 2048);
        async16(d2 + i * 2048, g2 + i * 2048);
      }
    }

    // bias vectors for this chunk: v[r] needs b1[c*32 + (r&3) + 8*(r>>2) + 4*q2]
    // -> 4 broadcast float4 reads (uniform per q2-half, conflict-free)
    float4 bb[4];
    #pragma unroll
    for (int g = 0; g < 4; ++g)
      bb[g] = *(const float4*)&sB1[c * 32 + 4 * q2 + 8 * g];

    // fc1 SWAPPED: Hc^T tile = W1c @ X^T; lane holds C[h=crow(r,q2)][xrow=l32].
    // A/B frag layouts are identical -> same register data, just swapped args.
    f32x16 h0, h1;
    #pragma unroll
    for (int j = 0; j < 16; ++j) { h0[j] = 0.f; h1[j] = 0.f; }
    __builtin_amdgcn_s_setprio(1);
    #pragma unroll
    for (int kf = 0; kf < 8; ++kf) {
      short8 wa = *(const short8*)&sW1[cur][kf * 512 + lane * 8];
      short8 wb = *(const short8*)&sW1[cur][(kf + 8) * 512 + lane * 8];
      h0 = __builtin_amdgcn_mfma_f32_32x32x16_bf16(wa, xf[kf],     h0, 0, 0, 0);
      h1 = __builtin_amdgcn_mfma_f32_32x32x16_bf16(wb, xf[kf + 8], h1, 0, 0, 0);
    }
    __builtin_amdgcn_s_setprio(0);

    // bias + relu in C-space
    float v[16];
    #pragma unroll
    for (int r = 0; r < 16; ++r) {
      float t = h0[r] + h1[r] + bb[r >> 2][r & 3];
      v[r] = t > 0.f ? t : 0.f;
    }

    // pack to fc2 A-frags in-register: cvt_pk pairs + permlane32_swap exchanges
    // {h4..7}<->{h8..11} halves between lane l and l+32. af[kf2] lane layout:
    // Hc[row=l32][h = kf2*16 + q2*8 + j].
    unsigned W0 = cvtpk_bf16(v[0],  v[1]),  W1 = cvtpk_bf16(v[2],  v[3]);
    unsigned W2 = cvtpk_bf16(v[4],  v[5]),  W3 = cvtpk_bf16(v[6],  v[7]);
    unsigned W4 = cvtpk_bf16(v[8],  v[9]),  W5 = cvtpk_bf16(v[10], v[11]);
    unsigned W6 = cvtpk_bf16(v[12], v[13]), W7 = cvtpk_bf16(v[14], v[15]);
    plswap(W0, W2); plswap(W1, W3); plswap(W4, W6); plswap(W5, W7);
    union { uint4v u; short8 s; } A0, A1;
    A0.u = (uint4v){W0, W1, W2, W3};
    A1.u = (uint4v){W4, W5, W6, W7};

    // fc2: acc[32 rows][256 cols] += Hc @ W2c^T (K=32 = two 32x32x16 steps)
    __builtin_amdgcn_s_setprio(1);
    #pragma unroll
    for (int cf = 0; cf < 8; ++cf) {
      short8 b0 = *(const short8*)&sW2[cur][(cf * 2 + 0) * 512 + lane * 8];
      short8 b1f = *(const short8*)&sW2[cur][(cf * 2 + 1) * 512 + lane * 8];
      acc[cf] = __builtin_amdgcn_mfma_f32_32x32x16_bf16(A0.s, b0,  acc[cf], 0, 0, 0);
      acc[cf] = __builtin_amdgcn_mfma_f32_32x32x16_bf16(A1.s, b1f, acc[cf], 0, 0, 0);
    }
    __builtin_amdgcn_s_setprio(0);

    __syncthreads();  // buf[cur] fully consumed; stage(c+1) landed
  }

  // epilogue: + b2, store fp32 (coalesced along l32)
  #pragma unroll
  for (int cf = 0; cf < 8; ++cf) {
    int col = cf * 32 + l32;
    float bias = b2[col];
    #pragma unroll
    for (int r = 0; r < 16; ++r) {
      long row = rowBase + (r & 3) + 8 * (r >> 2) + 4 * q2;
      Y[row * D_MODEL + col] = acc[cf][r] + bias;
    }
  }
}

extern "C" void kernel_launch(void* const* d_in, const int* in_sizes, int n_in,
                              void* d_out, int out_size, void* d_ws, size_t ws_size,
                              hipStream_t stream) {
  const float* x    = (const float*)d_in[0];
  const float* w1   = (const float*)d_in[1];
  const float* b1   = (const float*)d_in[2];
  const float* w2   = (const float*)d_in[3];
  const float* b2   = (const float*)d_in[4];
  const int*   mask = (const int*)d_in[5];

  unsigned short* W1p = (unsigned short*)d_ws;          // 512 KB
  unsigned short* W2p = W1p + (size_t)D_HID * D_MODEL;  // 512 KB
  float* Y = (float*)d_out;

  prep_weights<<<256, 256, 0, stream>>>(w1, w2, mask, W1p, W2p);
  ffd_fused<<<131072 / MT, 256, 0, stream>>>(x, b1, b2, W1p, W2p, Y);
}